// Round 22
// baseline (119.866 us; speedup 1.0000x reference)
//
#include <hip/hip_runtime.h>

#define B_ 64
#define L_ 1024
#define M_ 256
#define F_ 256

typedef __attribute__((ext_vector_type(8))) short short8;    // 8 bf16 (4 VGPR)
typedef __attribute__((ext_vector_type(16))) float f32x16;   // 32x32 MFMA C/D
typedef unsigned int u32;

struct Frag3 { short8 h, m, l; };

__device__ __forceinline__ u32 asu(float f) { union { float f; u32 u; } c; c.f = f; return c.u; }
__device__ __forceinline__ float asf(u32 u) { union { float f; u32 u; } c; c.u = u; return c.f; }
__device__ __forceinline__ u32 pack2(u32 lo, u32 hi) {
    return __builtin_amdgcn_perm(hi, lo, 0x07060302u);
}
__device__ __forceinline__ float4 ld4(const float* p) {
    return *reinterpret_cast<const float4*>(p);
}

// Async 16B global->LDS DMA; LDS dest wave-uniform, per-lane source carries
// the XOR swizzle (m173 pattern, validated R6/R10).
__device__ __forceinline__ void async_cp16(const float* g, float* l) {
    __builtin_amdgcn_global_load_lds(
        (const __attribute__((address_space(1))) u32*)g,
        (__attribute__((address_space(3))) u32*)l,
        16, 0, 0);
}

// Exact 3-way bf16 truncation split of 8 fp32: x = h + m + l (top 24 mantissa bits).
__device__ __forceinline__ Frag3 split8(float4 a, float4 b) {
    float x[8] = {a.x, a.y, a.z, a.w, b.x, b.y, b.z, b.w};
    u32 xb[8], rb[8], sb[8];
#pragma unroll
    for (int e = 0; e < 8; ++e) {
        xb[e] = asu(x[e]);
        float hf = asf(xb[e] & 0xFFFF0000u);
        float r  = x[e] - hf;                 // exact
        rb[e] = asu(r);
        float mf = asf(rb[e] & 0xFFFF0000u);
        float r2 = r - mf;                    // exact
        sb[e] = asu(r2);
    }
    union { u32 w[4]; short8 s; } H, M, Lo;
#pragma unroll
    for (int d = 0; d < 4; ++d) {
        H.w[d]  = pack2(xb[2 * d], xb[2 * d + 1]);
        M.w[d]  = pack2(rb[2 * d], rb[2 * d + 1]);
        Lo.w[d] = pack2(sb[2 * d], sb[2 * d + 1]);
    }
    Frag3 f; f.h = H.s; f.m = M.s; f.l = Lo.s; return f;
}

#define MFMA6(ACC, A, Bf)                                                        \
    ACC = __builtin_amdgcn_mfma_f32_32x32x16_bf16((A).m, (Bf).m, ACC, 0, 0, 0);  \
    ACC = __builtin_amdgcn_mfma_f32_32x32x16_bf16((A).h, (Bf).l, ACC, 0, 0, 0);  \
    ACC = __builtin_amdgcn_mfma_f32_32x32x16_bf16((A).l, (Bf).h, ACC, 0, 0, 0);  \
    ACC = __builtin_amdgcn_mfma_f32_32x32x16_bf16((A).h, (Bf).m, ACC, 0, 0, 0);  \
    ACC = __builtin_amdgcn_mfma_f32_32x32x16_bf16((A).m, (Bf).h, ACC, 0, 0, 0);  \
    ACC = __builtin_amdgcn_mfma_f32_32x32x16_bf16((A).h, (Bf).h, ACC, 0, 0, 0)

// One block per l, 256 threads = 4 waves, single-buffered LDS 40960 B (R20
// staging verbatim). NEW: square wave->tile mapping — wave w covers BOTH
// b-tiles x m-tiles {2w, 2w+1}: 4 splits per kk for 4 MFMA6-pairs
// (1.0 splits/pair vs R13's 1.5) -> block split work 384 -> 256 per l, with
// zero staging/barrier/numeric changes (same per-(b,m) chain -> absmax 0).
// D layout: col(m)=lane&31, row=(reg&3)+8*(reg>>2)+4*(lane>>5)  [m74/m101].
__launch_bounds__(256)
__global__ void mq_mfma_sq_kernel(const float* __restrict__ patch,
                                  const float* __restrict__ queue,
                                  float* __restrict__ out) {
    const int l    = blockIdx.x;
    const int t    = threadIdx.x;
    const int lane = t & 63;
    const int w    = t >> 6;        // 0..3: m-tile group (tiles 2w, 2w+1)
    const int r32  = lane & 31;
    const int kh   = lane >> 5;     // k-half: f-offset kh*8

    __shared__ __align__(16) float Ql[256 * 32];  // 32KB, slot = chunk^(row&7)
    __shared__ __align__(16) float Pl[64 * 32];   //  8KB   (total 40960 B)

    // staging geometry (R6/R20, proven): wave w stages Q rows w*64..+63
    // (8 chunks) and P rows w*16..+15 (2 chunks); source chunk lcol^lrow.
    const int lrow = lane >> 3;     // 0..7: row within an 8-row chunk
    const int lcol = lane & 7;      // 0..7: 16B slot within a 128B row
    const float* qsrcw = queue + ((size_t)l * M_ + w * 64 + lrow) * F_ + (lcol ^ lrow) * 4;
    const float* psrcw = patch + ((size_t)(w * 16 + lrow) * L_ + l) * F_ + (lcol ^ lrow) * 4;

    f32x16 acc00 = (f32x16)0.f, acc01 = (f32x16)0.f;   // bt0 x {mt0, mt1}
    f32x16 acc10 = (f32x16)0.f, acc11 = (f32x16)0.f;   // bt1 x {mt0, mt1}

    const int s7  = r32 & 7;          // read-side XOR (row&7 == r32&7 everywhere)
    const int ra0 = r32;              // P row, b-tile 0
    const int ra1 = 32 + r32;         // P row, b-tile 1
    const int rb0 = (w * 2) * 32 + r32;       // Q row, m-tile 2w
    const int rb1 = (w * 2 + 1) * 32 + r32;   // Q row, m-tile 2w+1

#pragma unroll 1
    for (int ft = 0; ft < 8; ++ft) {
        // barrier#1: all waves done reading tile ft-1 -> buffer reusable.
        __builtin_amdgcn_s_barrier();
        __builtin_amdgcn_sched_barrier(0);
        {
            const int o = ft * 32;
#pragma unroll
            for (int k = 0; k < 8; ++k)
                async_cp16(qsrcw + (size_t)k * 8 * F_ + o, &Ql[(w * 8 + k) * 256]);
#pragma unroll
            for (int k = 0; k < 2; ++k)
                async_cp16(psrcw + (size_t)k * 8 * L_ * F_ + o, &Pl[(w * 2 + k) * 256]);
        }
        asm volatile("s_waitcnt vmcnt(0)" ::: "memory");
        __builtin_amdgcn_sched_barrier(0);
        // barrier#2: every wave's tile-ft chunks landed.
        __builtin_amdgcn_s_barrier();
        __builtin_amdgcn_sched_barrier(0);

#pragma unroll
        for (int kk = 0; kk < 2; ++kk) {
            const int c0 = kk * 4 + kh * 2;   // first 16B chunk of this fragment
            const Frag3 A0 = split8(ld4(&Pl[ra0 * 32 + ((c0 ^ s7) * 4)]),
                                    ld4(&Pl[ra0 * 32 + (((c0 + 1) ^ s7) * 4)]));
            const Frag3 A1 = split8(ld4(&Pl[ra1 * 32 + ((c0 ^ s7) * 4)]),
                                    ld4(&Pl[ra1 * 32 + (((c0 + 1) ^ s7) * 4)]));
            {
                const Frag3 Bf = split8(ld4(&Ql[rb0 * 32 + ((c0 ^ s7) * 4)]),
                                        ld4(&Ql[rb0 * 32 + (((c0 + 1) ^ s7) * 4)]));
                MFMA6(acc00, A0, Bf);
                MFMA6(acc10, A1, Bf);
            }
            {
                const Frag3 Bf = split8(ld4(&Ql[rb1 * 32 + ((c0 ^ s7) * 4)]),
                                        ld4(&Ql[rb1 * 32 + (((c0 + 1) ^ s7) * 4)]));
                MFMA6(acc01, A0, Bf);
                MFMA6(acc11, A1, Bf);
            }
        }
    }

    __syncthreads();   // all compute done before scratch overlays Pl

    // argmax over m per b (numpy first-occurrence). Wave partial over its
    // 64 m-cols [w*64, w*64+64) for ALL 64 b-rows; in-lane mt0->mt1
    // ascending m, strict '>' keeps lowest m; butterfly prefers lower idx.
    float* pval = (float*)&Pl[0];          // [4][64]
    int*   pidx = (int*)&Pl[0] + 256;      // [4][64]
    int*   sidx = (int*)&Pl[0] + 512;      // [64]
#pragma unroll
    for (int r = 0; r < 16; ++r) {
        const int crow = (r & 3) + 8 * (r >> 2) + 4 * kh;
        // ---- b-tile 0 ----
        {
            float bv = acc00[r];
            int   bi = w * 64 + r32;
            {
                const float cv = acc01[r];
                const int   ci = w * 64 + 32 + r32;
                if (cv > bv) { bv = cv; bi = ci; }
            }
#pragma unroll
            for (int off = 16; off >= 1; off >>= 1) {
                const float ov = __shfl_xor(bv, off);
                const int   oi = __shfl_xor(bi, off);
                if (ov > bv || (ov == bv && oi < bi)) { bv = ov; bi = oi; }
            }
            if (r32 == 0) { pval[w * 64 + crow] = bv; pidx[w * 64 + crow] = bi; }
        }
        // ---- b-tile 1 ----
        {
            float bv = acc10[r];
            int   bi = w * 64 + r32;
            {
                const float cv = acc11[r];
                const int   ci = w * 64 + 32 + r32;
                if (cv > bv) { bv = cv; bi = ci; }
            }
#pragma unroll
            for (int off = 16; off >= 1; off >>= 1) {
                const float ov = __shfl_xor(bv, off);
                const int   oi = __shfl_xor(bi, off);
                if (ov > bv || (ov == bv && oi < bi)) { bv = ov; bi = oi; }
            }
            if (r32 == 0) { pval[w * 64 + 32 + crow] = bv; pidx[w * 64 + 32 + crow] = bi; }
        }
    }
    __syncthreads();

    // Combine the four m-quarters; ascending w with strict '>' keeps the
    // lowest m on ties -> numpy first-occurrence.
    if (t < 64) {
        float bv = pval[t];
        int   bi = pidx[t];
#pragma unroll
        for (int g = 1; g < 4; ++g) {
            const float cv = pval[g * 64 + t];
            if (cv > bv) { bv = cv; bi = pidx[g * 64 + t]; }
        }
        sidx[t] = bi;
    }
    __syncthreads();

    // gather: out[b][l][:] = queue[l][sidx[b]][:]  (queue[l] is L2-hot)
    const int cb = t >> 6;     // 0..3
    const int cc = t & 63;     // float4 index within the 256-float row
#pragma unroll
    for (int b0 = 0; b0 < 64; b0 += 4) {
        const int b  = b0 + cb;
        const int mi = sidx[b];
        const float4 v = ld4(&queue[((size_t)l * M_ + mi) * F_ + cc * 4]);
        *reinterpret_cast<float4*>(&out[((size_t)b * L_ + l) * F_ + cc * 4]) = v;
    }
}

extern "C" void kernel_launch(void* const* d_in, const int* in_sizes, int n_in,
                              void* d_out, int out_size, void* d_ws, size_t ws_size,
                              hipStream_t stream) {
    const float* patch = (const float*)d_in[0];
    const float* queue = (const float*)d_in[1];
    float* out = (float*)d_out;
    mq_mfma_sq_kernel<<<dim3(L_), dim3(256), 0, stream>>>(patch, queue, out);
}